// Round 1
// baseline (74.837 us; speedup 1.0000x reference)
//
#include <hip/hip_runtime.h>

#define NF 13          // y = [1, x1..x12]
#define NEXP 454       // unique monomials
#define NROWS 65536
#define BN_EPS 1e-5f

// Decode feature index j (0..453) -> nondecreasing triple (i0<=i1<=i2),
// lexicographic order over (i0,i1,i2), skipping (0,0,0).
__device__ __forceinline__ void decode_triple(int j, int& i0, int& i1, int& i2) {
    int g = j + 1;  // global rank among all 455 nondecreasing triples
    i0 = 0;
    for (;;) {
        int m = NF - i0;
        int c = m * (m + 1) / 2;     // triples with this i0
        if (g < c) break;
        g -= c; ++i0;
    }
    i1 = i0;
    for (;;) {
        int m = NF - i1;             // triples with this (i0,i1)
        if (g < m) break;
        g -= m; ++i1;
    }
    i2 = i1 + g;
}

// ---------------- Pass 1: per-feature sum and sum-of-squares ----------------
template <int ROWS>
__global__ __launch_bounds__(256) void stats_kernel(const float* __restrict__ x,
                                                    float* __restrict__ sums) {
    __shared__ float y[ROWS][NF];
    const int tid = threadIdx.x;
    const int row0 = blockIdx.x * ROWS;

    // Stage x chunk -> LDS as y rows (coalesced: contiguous 12*ROWS floats)
    for (int idx = tid; idx < ROWS * 12; idx += 256) {
        int r = idx / 12, c = idx - r * 12;
        y[r][c + 1] = x[(size_t)row0 * 12 + idx];
    }
    for (int r = tid; r < ROWS; r += 256) y[r][0] = 1.0f;
    __syncthreads();

    const int j0 = tid;            // always < 454 since blockDim=256
    const int j1 = tid + 256;
    const bool has1 = (j1 < NEXP);
    int a0, a1, a2, b0 = 0, b1 = 0, b2 = 0;
    decode_triple(j0, a0, a1, a2);
    if (has1) decode_triple(j1, b0, b1, b2);

    float s0 = 0.f, q0 = 0.f, s1 = 0.f, q1 = 0.f;
    #pragma unroll 4
    for (int r = 0; r < ROWS; ++r) {
        float f0 = y[r][a0] * y[r][a1] * y[r][a2];
        s0 += f0; q0 += f0 * f0;
        if (has1) {
            float f1 = y[r][b0] * y[r][b1] * y[r][b2];
            s1 += f1; q1 += f1 * f1;
        }
    }
    atomicAdd(&sums[j0], s0);
    atomicAdd(&sums[NEXP + j0], q0);
    if (has1) {
        atomicAdd(&sums[j1], s1);
        atomicAdd(&sums[NEXP + j1], q1);
    }
}

// ---------------- Pass 2: fold BN stats into scale/shift --------------------
__global__ __launch_bounds__(256) void finalize_kernel(const float* __restrict__ sums,
                                                       const float* __restrict__ w,
                                                       const float* __restrict__ b,
                                                       float* __restrict__ ss) {
    int j = blockIdx.x * 256 + threadIdx.x;
    if (j >= NEXP) return;
    const float inv_n = 1.0f / (float)NROWS;
    float mean = sums[j] * inv_n;
    float var  = sums[NEXP + j] * inv_n - mean * mean;
    float scale = rsqrtf(var + BN_EPS) * w[j];
    ss[j] = scale;
    ss[NEXP + j] = b[j] - mean * scale;
}

// ---------------- Pass 3: recompute feats, apply affine, store --------------
template <int ROWS>
__global__ __launch_bounds__(256) void write_kernel(const float* __restrict__ x,
                                                    const float* __restrict__ ss,
                                                    float* __restrict__ out) {
    __shared__ float y[ROWS][NF];
    __shared__ float sc[NEXP];
    __shared__ float sh[NEXP];
    const int tid = threadIdx.x;
    const int row0 = blockIdx.x * ROWS;

    for (int idx = tid; idx < ROWS * 12; idx += 256) {
        int r = idx / 12, c = idx - r * 12;
        y[r][c + 1] = x[(size_t)row0 * 12 + idx];
    }
    for (int r = tid; r < ROWS; r += 256) y[r][0] = 1.0f;
    for (int j = tid; j < NEXP; j += 256) {
        sc[j] = ss[j];
        sh[j] = ss[NEXP + j];
    }
    __syncthreads();

    const int j0 = tid;
    const int j1 = tid + 256;
    const bool has1 = (j1 < NEXP);
    int a0, a1, a2, b0 = 0, b1 = 0, b2 = 0;
    decode_triple(j0, a0, a1, a2);
    if (has1) decode_triple(j1, b0, b1, b2);
    const float sc0 = sc[j0], sh0 = sh[j0];
    const float sc1 = has1 ? sc[j1] : 0.f, sh1 = has1 ? sh[j1] : 0.f;

    for (int r = 0; r < ROWS; ++r) {
        float* o = out + (size_t)(row0 + r) * NEXP;
        float f0 = y[r][a0] * y[r][a1] * y[r][a2];
        o[j0] = f0 * sc0 + sh0;
        if (has1) {
            float f1 = y[r][b0] * y[r][b1] * y[r][b2];
            o[j1] = f1 * sc1 + sh1;
        }
    }
}

extern "C" void kernel_launch(void* const* d_in, const int* in_sizes, int n_in,
                              void* d_out, int out_size, void* d_ws, size_t ws_size,
                              hipStream_t stream) {
    const float* x  = (const float*)d_in[0];
    const float* bw = (const float*)d_in[1];
    const float* bb = (const float*)d_in[2];
    float* out = (float*)d_out;
    float* ws  = (float*)d_ws;   // [0..907]=sum,sumsq  [908..1815]=scale,shift

    // Zero the accumulators every call (ws is poisoned once, never restored).
    hipMemsetAsync(ws, 0, 2 * NEXP * sizeof(float), stream);

    constexpr int SROWS = 64;
    stats_kernel<SROWS><<<NROWS / SROWS, 256, 0, stream>>>(x, ws);

    finalize_kernel<<<2, 256, 0, stream>>>(ws, bw, bb, ws + 2 * NEXP);

    constexpr int WROWS = 16;
    write_kernel<WROWS><<<NROWS / WROWS, 256, 0, stream>>>(x, ws + 2 * NEXP, out);
}